// Round 11
// baseline (2507.634 us; speedup 1.0000x reference)
//
#include <hip/hip_runtime.h>
#include <hip/hip_bf16.h>
#include <math.h>

// GGNN: L=5 layers of { m = h@W_l ; agg = scatter_add(ew * m[src] -> dst) ;
//                       h = GRUCell(agg, h) } then out = relu(h)@fc_w^T + fc_b
// H=256, N=50000, E=800000.
//
// R10 (m97-structure 128x128 GEMM) took gates 412->230us, MfmaUtil 41%.
// R11: (1) BK=64 (2 chunks per barrier-phase; 16 MFMA/barrier = m97 parity;
// LDS 32KB); (2) sigmoid/tanh via __expf + v_rcp (epilogue was ~30% VALU);
// (3) spmm unrolled to 4 independent gathers in flight.

#define HDIM 256

using bf16x8 = __attribute__((ext_vector_type(8))) short;
using f32x4  = __attribute__((ext_vector_type(4))) float;

__device__ __forceinline__ bf16x8 ldfrag(const ushort* p) {
    union { uint4 u; bf16x8 f; } x;
    x.u = *(const uint4*)p;
    return x.f;
}
#define MFMA(a, b, c) __builtin_amdgcn_mfma_f32_16x16x32_bf16((a), (b), (c), 0, 0, 0)
#define GLD16(g, l)                                                            \
    __builtin_amdgcn_global_load_lds(                                          \
        (const __attribute__((address_space(1))) void*)(g),                    \
        (__attribute__((address_space(3))) void*)(l), 16, 0, 0)

__device__ __forceinline__ float ldf(const void* p, size_t i, int isbf) {
    if (isbf) return __bfloat162float(((const __hip_bfloat16*)p)[i]);
    return ((const float*)p)[i];
}
__device__ __forceinline__ ushort f2bs(float v) {
    __hip_bfloat16 b = __float2bfloat16(v);
    return *(ushort*)&b;
}
__device__ __forceinline__ float bs2f(ushort u) {
    __hip_bfloat16 b = *(__hip_bfloat16*)&u;
    return __bfloat162float(b);
}
// fast sigmoid/tanh: v_exp_f32 + v_rcp_f32 (~1e-7 rel err, fine vs 4e-3 bar)
__device__ __forceinline__ float sigm(float x) {
    return __builtin_amdgcn_rcpf(1.f + __expf(-x));
}
__device__ __forceinline__ float ftanh(float x) {
    return 2.f * __builtin_amdgcn_rcpf(1.f + __expf(-2.f * x)) - 1.f;
}
// tiled plane addr, K-extent 256 (h planes)
__device__ __forceinline__ size_t taddrH(int n, int k) {
    return (size_t)(n >> 4) * 4096 + (size_t)((k >> 5) << 9)
         + (size_t)(((k >> 3) & 3) << 7) + (size_t)((n & 15) << 3) + (k & 7);
}
// tiled plane addr, K-extent 512 (agg hi|lo combined)
__device__ __forceinline__ size_t taddrA(int n, int k) {
    return (size_t)(n >> 4) * 8192 + (size_t)((k >> 5) << 9)
         + (size_t)(((k >> 3) & 3) << 7) + (size_t)((n & 15) << 3) + (k & 7);
}

// flags[0] = 1 if float tensors are bf16, 0 if f32
// flags[1] = 1 if edge_index is int64, 0 if int32
__global__ void detect_k(const void* x, const void* ei, int* flags) {
    if (blockIdx.x == 0 && threadIdx.x == 0) {
        const __hip_bfloat16* xb = (const __hip_bfloat16*)x;
        int isbf = 1;
        for (int i = 0; i < 1024; ++i) {
            float v = fabsf(__bfloat162float(xb[i]));
            if (!(v < 1e6f)) { isbf = 0; break; }
        }
        flags[0] = isbf;
        const int* e32 = (const int*)ei;
        int orv = e32[1] | e32[3] | e32[5] | e32[7] | e32[9] | e32[11];
        flags[1] = (orv == 0) ? 1 : 0;
    }
}

// x -> h planes (tiled); pad rows zeroed
__global__ void conv_h0_k(const void* x, ushort* HH, ushort* HL,
                          const int* flags, int useHL, int Nn, size_t npad256) {
    size_t i = (size_t)blockIdx.x * blockDim.x + threadIdx.x;
    if (i >= npad256) return;
    const int n = (int)(i >> 8), k = (int)(i & 255);
    float v = 0.f;
    if (n < Nn) v = ldf(x, i, flags[0]);
    const ushort hi = f2bs(v);
    const size_t a = taddrH(n, k);
    HH[a] = hi;
    if (useHL) HL[a] = f2bs(v - bs2f(hi));
}

// Build tiled B matrices + biases (same logical layout as R10).
__global__ void prep_k(const void* w, const void* wih, const void* whh,
                       const void* bih, const void* bhh,
                       ushort* BgH, ushort* BgL, ushort* BwH, ushort* BwL,
                       float* bsum, float* bni, float* bnh,
                       const int* flags, int L) {
    int i = blockIdx.x * blockDim.x + threadIdx.x;
    int isbf = flags[0];
    if (i < 1048576) {
        const int j = i >> 10, k = i & 1023;
        const int g = (j >> 4) & 3, b = ((j >> 6) << 4) + (j & 15);
        const int kk = k & 255, seg = k >> 8;
        float v = 0.f;
        if (g == 0) v = (seg < 2) ? ldf(wih, (size_t)b * 256 + kk, isbf)
                                  : ldf(whh, (size_t)b * 256 + kk, isbf);
        else if (g == 1) v = (seg < 2) ? ldf(wih, (size_t)(256 + b) * 256 + kk, isbf)
                                       : ldf(whh, (size_t)(256 + b) * 256 + kk, isbf);
        else if (g == 2) v = (seg < 2) ? ldf(wih, (size_t)(512 + b) * 256 + kk, isbf) : 0.f;
        else             v = (seg < 2) ? 0.f : ldf(whh, (size_t)(512 + b) * 256 + kk, isbf);
        const ushort hi = f2bs(v);
        const int ct = j >> 4, c = k >> 5;
        const size_t a = (size_t)(ct * 32 + c) * 512
                       + (size_t)(((k >> 3) & 3) << 7) + ((j & 15) << 3) + (k & 7);
        BgH[a] = hi; BgL[a] = f2bs(v - bs2f(hi));
    }
    if (i < L * 131072) {
        const int l = i >> 17, r2 = i & 131071;
        const int j = r2 >> 9, k = r2 & 511;
        const int kk = k & 255;
        const float v = ldf(w, ((size_t)l << 16) + (size_t)kk * 256 + j, isbf);
        const ushort hi = f2bs(v);
        const int ct = j >> 4, c = k >> 5;
        const size_t a = (size_t)l * 131072 + (size_t)(ct * 16 + c) * 512
                       + (size_t)(((k >> 3) & 3) << 7) + ((j & 15) << 3) + (k & 7);
        BwH[a] = hi; BwL[a] = f2bs(v - bs2f(hi));
    }
    if (i < 512) bsum[i] = ldf(bih, i, isbf) + ldf(bhh, i, isbf);
    if (i < 256) {
        bni[i] = ldf(bih, 512 + i, isbf);
        bnh[i] = ldf(bhh, 512 + i, isbf);
    }
}

// ---------------- CSR build (by dst), once per call ----------------

__global__ void zero_int_k(int* p, int n) {
    int i = blockIdx.x * blockDim.x + threadIdx.x;
    if (i < n) p[i] = 0;
}

__global__ void count_k(const void* ei, int* cnt, const int* flags, int E) {
    int e = blockIdx.x * blockDim.x + threadIdx.x;
    if (e >= E) return;
    const int* e32 = (const int*)ei;
    int d = flags[1] ? e32[2 * ((size_t)E + e)] : e32[(size_t)E + e];
    atomicAdd(&cnt[d], 1);
}

__global__ __launch_bounds__(256)
void scan1_k(const int* cnt, int* ptr, int* bsumN, int N) {
    __shared__ int s[256];
    const int t = threadIdx.x;
    const int gid = blockIdx.x * 256 + t;
    int v = (gid < N) ? cnt[gid] : 0;
    const int own = v;
    s[t] = v;
    __syncthreads();
#pragma unroll
    for (int off = 1; off < 256; off <<= 1) {
        int add = (t >= off) ? s[t - off] : 0;
        __syncthreads();
        s[t] += add;
        __syncthreads();
    }
    if (gid < N) ptr[gid] = s[t] - own;
    if (t == 255) bsumN[blockIdx.x] = s[255];
}

__global__ __launch_bounds__(256)
void scan2_k(int* bsumN, int NB) {
    __shared__ int s[256];
    __shared__ int carry;
    const int t = threadIdx.x;
    if (t == 0) carry = 0;
    __syncthreads();
    for (int base = 0; base < NB; base += 256) {
        const int i = base + t;
        int v = (i < NB) ? bsumN[i] : 0;
        const int own = v;
        s[t] = v;
        __syncthreads();
#pragma unroll
        for (int off = 1; off < 256; off <<= 1) {
            int add = (t >= off) ? s[t - off] : 0;
            __syncthreads();
            s[t] += add;
            __syncthreads();
        }
        if (i < NB) bsumN[i] = carry + s[t] - own;
        __syncthreads();
        if (t == 0) carry += s[255];
        __syncthreads();
    }
}

__global__ void scan3_k(int* ptr, int* cursor, const int* bsumN, int N, int E) {
    const int gid = blockIdx.x * 256 + threadIdx.x;
    if (gid < N) {
        const int p = ptr[gid] + bsumN[blockIdx.x];
        ptr[gid] = p;
        cursor[gid] = p;
    }
    if (gid == 0) ptr[N] = E;
}

__global__ void fill_k(const void* ei, const void* ew, int* cursor,
                       int* srcs, float* wse, const int* flags, int E) {
    int e = blockIdx.x * blockDim.x + threadIdx.x;
    if (e >= E) return;
    const int* e32 = (const int*)ei;
    int s, d;
    if (flags[1]) { s = e32[2 * (size_t)e]; d = e32[2 * ((size_t)E + e)]; }
    else          { s = e32[e];             d = e32[(size_t)E + e]; }
    const int p = atomicAdd(&cursor[d], 1);
    srcs[p] = s;
    wse[p] = ldf(ew, e, flags[0]);
}

// ---------------- SpMM gather: agg[d] = sum_j w_j * m[src_j] ----------------
// 4 independent 1KB gathers in flight per wave; AGG tiled hi|lo plane.
__global__ __launch_bounds__(256)
void spmm_k(const float* __restrict__ m, const int* __restrict__ ptr,
            const int* __restrict__ srcs, const float* __restrict__ wse,
            ushort* __restrict__ AGG, int N) {
    const int node = blockIdx.x * 4 + (threadIdx.x >> 6);
    if (node >= N) return;
    const int lane4 = (threadIdx.x & 63) << 2;
    const int p0 = ptr[node], p1 = ptr[node + 1];
    float4 acc = make_float4(0.f, 0.f, 0.f, 0.f);
    int j = p0;
    for (; j + 3 < p1; j += 4) {
        const int s0 = srcs[j], s1 = srcs[j + 1], s2 = srcs[j + 2], s3 = srcs[j + 3];
        const float w0 = wse[j], w1 = wse[j + 1], w2 = wse[j + 2], w3 = wse[j + 3];
        const float4 v0 = *(const float4*)&m[(size_t)s0 * HDIM + lane4];
        const float4 v1 = *(const float4*)&m[(size_t)s1 * HDIM + lane4];
        const float4 v2 = *(const float4*)&m[(size_t)s2 * HDIM + lane4];
        const float4 v3 = *(const float4*)&m[(size_t)s3 * HDIM + lane4];
        acc.x = fmaf(w0, v0.x, acc.x); acc.y = fmaf(w0, v0.y, acc.y);
        acc.z = fmaf(w0, v0.z, acc.z); acc.w = fmaf(w0, v0.w, acc.w);
        acc.x = fmaf(w1, v1.x, acc.x); acc.y = fmaf(w1, v1.y, acc.y);
        acc.z = fmaf(w1, v1.z, acc.z); acc.w = fmaf(w1, v1.w, acc.w);
        acc.x = fmaf(w2, v2.x, acc.x); acc.y = fmaf(w2, v2.y, acc.y);
        acc.z = fmaf(w2, v2.z, acc.z); acc.w = fmaf(w2, v2.w, acc.w);
        acc.x = fmaf(w3, v3.x, acc.x); acc.y = fmaf(w3, v3.y, acc.y);
        acc.z = fmaf(w3, v3.z, acc.z); acc.w = fmaf(w3, v3.w, acc.w);
    }
    for (; j < p1; ++j) {
        const int s0 = srcs[j];
        const float w0 = wse[j];
        const float4 v0 = *(const float4*)&m[(size_t)s0 * HDIM + lane4];
        acc.x = fmaf(w0, v0.x, acc.x); acc.y = fmaf(w0, v0.y, acc.y);
        acc.z = fmaf(w0, v0.z, acc.z); acc.w = fmaf(w0, v0.w, acc.w);
    }
    ushort4 hi, lo;
    hi.x = f2bs(acc.x); lo.x = f2bs(acc.x - bs2f(hi.x));
    hi.y = f2bs(acc.y); lo.y = f2bs(acc.y - bs2f(hi.y));
    hi.z = f2bs(acc.z); lo.z = f2bs(acc.z - bs2f(hi.z));
    hi.w = f2bs(acc.w); lo.w = f2bs(acc.w - bs2f(hi.w));
    *(ushort4*)&AGG[taddrA(node, lane4)] = hi;
    *(ushort4*)&AGG[taddrA(node, 256 + lane4)] = lo;
}

// ---------------- m97-style GEMM #1: m = h @ Wt^T, BK=64 --------------------
// 128x128 tile, 4 waves, 64 acc f32/thread. Per phase: 2 chunks staged
// (A 16KB + B 16KB LDS), 2 barriers, 32 MFMAs (16/barrier). LDS layout
// [tile/ct 0..7][cc 0..1][512 halves]; fragments conflict-free ds_read_b128.
__global__ __launch_bounds__(256)
void m_gemm_k(const ushort* __restrict__ HH, const ushort* __restrict__ HL,
              const ushort* __restrict__ BwHl, const ushort* __restrict__ BwLl,
              float* __restrict__ m, const int* __restrict__ flags,
              int useHL, int nRB) {
    __shared__ ushort lds[16384];  // A 8192 | B 8192 halves (32 KB)
    const int rb = blockIdx.x >> 1, cgB = blockIdx.x & 1;
    if (rb >= nRB) return;
    const int tid = threadIdx.x, lane = tid & 63;
    const int wv = __builtin_amdgcn_readfirstlane(tid >> 6);
    const int wr = wv & 1, wc = wv >> 1;
    const int lm = lane & 15, lq = lane >> 4;
    const int fullsplit = !flags[0];
    const int NIT = useHL ? 8 : 4;
    const int rt = rb * 8, t0 = 2 * wv;
    f32x4 acc[4][4];
#pragma unroll
    for (int i = 0; i < 4; ++i)
#pragma unroll
        for (int j = 0; j < 4; ++j) acc[i][j] = (f32x4){0.f, 0.f, 0.f, 0.f};

    for (int t = 0; t < NIT; ++t) {
        __syncthreads();
        const ushort* ab = (t < 4) ? HH : HL;
        const int cA = (t < 4) ? 2 * t : 2 * (t - 4);
        const size_t a0 = (size_t)(rt + t0) * 4096 + (size_t)cA * 512 + (size_t)lane * 8;
        GLD16(ab + a0, &lds[(t0 * 2 + 0) * 512]);
        GLD16(ab + a0 + 512, &lds[(t0 * 2 + 1) * 512]);
        GLD16(ab + a0 + 4096, &lds[((t0 + 1) * 2 + 0) * 512]);
        GLD16(ab + a0 + 4608, &lds[((t0 + 1) * 2 + 1) * 512]);
        const size_t bb0 = ((size_t)(8 * cgB + t0) * 16 + 2 * t) * 512 + (size_t)lane * 8;
        GLD16(BwHl + bb0, &lds[8192 + (t0 * 2 + 0) * 512]);
        GLD16(BwHl + bb0 + 512, &lds[8192 + (t0 * 2 + 1) * 512]);
        GLD16(BwHl + bb0 + 8192, &lds[8192 + ((t0 + 1) * 2 + 0) * 512]);
        GLD16(BwHl + bb0 + 8704, &lds[8192 + ((t0 + 1) * 2 + 1) * 512]);
        __syncthreads();
#pragma unroll
        for (int cc = 0; cc < 2; ++cc) {
            bf16x8 af[4], bf[4];
#pragma unroll
            for (int i = 0; i < 4; ++i)
                af[i] = ldfrag(&lds[((4 * wr + i) * 2 + cc) * 512 + lq * 128 + lm * 8]);
#pragma unroll
            for (int j = 0; j < 4; ++j)
                bf[j] = ldfrag(&lds[8192 + ((4 * wc + j) * 2 + cc) * 512 + lq * 128 + lm * 8]);
#pragma unroll
            for (int i = 0; i < 4; ++i)
#pragma unroll
                for (int j = 0; j < 4; ++j) acc[i][j] = MFMA(af[i], bf[j], acc[i][j]);
            if (fullsplit) {
#pragma unroll
                for (int j = 0; j < 4; ++j) {
                    const bf16x8 bl = ldfrag(
                        &BwLl[((size_t)(8 * cgB + 4 * wc + j) * 16 + 2 * t + cc) * 512
                              + lq * 128 + lm * 8]);
#pragma unroll
                    for (int i = 0; i < 4; ++i) acc[i][j] = MFMA(af[i], bl, acc[i][j]);
                }
            }
        }
    }
#pragma unroll
    for (int i = 0; i < 4; ++i) {
        const int row = rb * 128 + wr * 64 + i * 16 + lq * 4;
#pragma unroll
        for (int j = 0; j < 4; ++j) {
            const int col = cgB * 128 + wc * 64 + j * 16 + lm;
#pragma unroll
            for (int v = 0; v < 4; ++v)
                m[(size_t)(row + v) * 256 + col] = acc[i][j][v];  // m padded
        }
    }
}

// ---------------- m97-style GEMM #2: gates + fused GRU, BK=64 ---------------
__global__ __launch_bounds__(256)
void gates_k(const ushort* __restrict__ AGG,
             const ushort* __restrict__ HH, const ushort* __restrict__ HL,
             const ushort* __restrict__ BgH, const ushort* __restrict__ BgL,
             const float* __restrict__ bsum, const float* __restrict__ bni,
             const float* __restrict__ bnh,
             ushort* __restrict__ HnH, ushort* __restrict__ HnL,
             const int* __restrict__ flags, int useHL, int nRB) {
    __shared__ ushort lds[16384];
    const int x = blockIdx.x & 7, rem = blockIdx.x >> 3;
    const int cgB = rem & 7, rbHi = rem >> 3;
    const int rb = rbHi * 8 + x;
    if (rb >= nRB) return;
    const int tid = threadIdx.x, lane = tid & 63;
    const int wv = __builtin_amdgcn_readfirstlane(tid >> 6);
    const int wr = wv & 1, wc = wv >> 1;
    const int lm = lane & 15, lq = lane >> 4;
    const int fullsplit = !flags[0];
    const int NIT = useHL ? 16 : 12;
    const int rt = rb * 8, t0 = 2 * wv;
    f32x4 acc[4][4];
#pragma unroll
    for (int i = 0; i < 4; ++i)
#pragma unroll
        for (int j = 0; j < 4; ++j) acc[i][j] = (f32x4){0.f, 0.f, 0.f, 0.f};

    for (int t = 0; t < NIT; ++t) {
        __syncthreads();
        const ushort* ab;
        size_t stride;
        int cA;
        if (t < 8)       { ab = AGG; stride = 8192; cA = 2 * t; }
        else if (t < 12) { ab = HH;  stride = 4096; cA = 2 * (t - 8); }
        else             { ab = HL;  stride = 4096; cA = 2 * (t - 12); }
        const size_t a0 = (size_t)(rt + t0) * stride + (size_t)cA * 512 + (size_t)lane * 8;
        GLD16(ab + a0, &lds[(t0 * 2 + 0) * 512]);
        GLD16(ab + a0 + 512, &lds[(t0 * 2 + 1) * 512]);
        GLD16(ab + a0 + stride, &lds[((t0 + 1) * 2 + 0) * 512]);
        GLD16(ab + a0 + stride + 512, &lds[((t0 + 1) * 2 + 1) * 512]);
        const size_t bb0 = ((size_t)(8 * cgB + t0) * 32 + 2 * t) * 512 + (size_t)lane * 8;
        GLD16(BgH + bb0, &lds[8192 + (t0 * 2 + 0) * 512]);
        GLD16(BgH + bb0 + 512, &lds[8192 + (t0 * 2 + 1) * 512]);
        GLD16(BgH + bb0 + 16384, &lds[8192 + ((t0 + 1) * 2 + 0) * 512]);
        GLD16(BgH + bb0 + 16896, &lds[8192 + ((t0 + 1) * 2 + 1) * 512]);
        __syncthreads();
#pragma unroll
        for (int cc = 0; cc < 2; ++cc) {
            bf16x8 af[4], bf[4];
#pragma unroll
            for (int i = 0; i < 4; ++i)
                af[i] = ldfrag(&lds[((4 * wr + i) * 2 + cc) * 512 + lq * 128 + lm * 8]);
#pragma unroll
            for (int j = 0; j < 4; ++j)
                bf[j] = ldfrag(&lds[8192 + ((4 * wc + j) * 2 + cc) * 512 + lq * 128 + lm * 8]);
#pragma unroll
            for (int i = 0; i < 4; ++i)
#pragma unroll
                for (int j = 0; j < 4; ++j) acc[i][j] = MFMA(af[i], bf[j], acc[i][j]);
            if (fullsplit) {
#pragma unroll
                for (int j = 0; j < 4; ++j) {
                    const bf16x8 bl = ldfrag(
                        &BgL[((size_t)(8 * cgB + 4 * wc + j) * 32 + 2 * t + cc) * 512
                             + lq * 128 + lm * 8]);
#pragma unroll
                    for (int i = 0; i < 4; ++i) acc[i][j] = MFMA(af[i], bl, acc[i][j]);
                }
            }
        }
    }
    // GRU epilogue: col-tile 0..3 = r,z,ni,nh for hidden unit b
    const int b = (2 * cgB + wc) * 16 + lm;
    const float rbias = bsum[b], zbias = bsum[256 + b];
    const float ibias = bni[b], hbias = bnh[b];
#pragma unroll
    for (int i = 0; i < 4; ++i) {
        const int row0 = rb * 128 + wr * 64 + i * 16 + lq * 4;
#pragma unroll
        for (int v = 0; v < 4; ++v) {
            const int row = row0 + v;
            const size_t ho = taddrH(row, b);  // buffers padded; pads benign
            float hold = bs2f(HH[ho]);
            if (useHL) hold += bs2f(HL[ho]);
            const float r = sigm(acc[i][0][v] + rbias);
            const float z = sigm(acc[i][1][v] + zbias);
            const float nn = ftanh(acc[i][2][v] + ibias + r * (acc[i][3][v] + hbias));
            const float hv = (1.f - z) * nn + z * hold;
            const ushort hi = f2bs(hv);
            HnH[ho] = hi;
            if (useHL) HnL[ho] = f2bs(hv - bs2f(hi));
        }
    }
}

// out[n] = sum_t relu(h[n,t]) * fc_w[t] + fc_b ; one 256-thread block per node
__global__ void final_k(const ushort* __restrict__ HH, const ushort* __restrict__ HL,
                        const void* fcw, const void* fcb,
                        void* out, const int* flags, int useHL, int N) {
    const int n = blockIdx.x;
    const int t = threadIdx.x;
    const int isbf = flags[0];
    const size_t off = taddrH(n, t);
    float h = bs2f(HH[off]);
    if (useHL) h += bs2f(HL[off]);
    float v = fmaxf(h, 0.f) * ldf(fcw, t, isbf);
#pragma unroll
    for (int offx = 32; offx >= 1; offx >>= 1) v += __shfl_down(v, offx);
    __shared__ float red[4];
    if ((t & 63) == 0) red[t >> 6] = v;
    __syncthreads();
    if (t == 0) {
        const float s = red[0] + red[1] + red[2] + red[3] + ldf(fcb, 0, isbf);
        if (isbf) ((__hip_bfloat16*)out)[n] = __float2bfloat16(s);
        else      ((float*)out)[n] = s;
    }
}

extern "C" void kernel_launch(void* const* d_in, const int* in_sizes, int n_in,
                              void* d_out, int out_size, void* d_ws, size_t ws_size,
                              hipStream_t stream) {
    const int H = HDIM;
    const int N = in_sizes[0] / H;       // 50000
    const int E = in_sizes[2];           // 800000
    const int L = in_sizes[3] / (H * H); // 5
    const int NB = (N + 255) / 256;
    const int nRB = (N + 127) / 128;     // 391
    const size_t NPAD = (size_t)nRB * 128;
    const size_t hHalf = NPAD * 256;     // halves per h plane
    const size_t aggHalf = NPAD * 512;

    char* p = (char*)d_ws;
    int*    flags = (int*)p;              p += 64;
    ushort* AGG  = (ushort*)p;            p += aggHalf * 2;
    ushort* HxH  = (ushort*)p;            p += hHalf * 2;
    ushort* HyH  = (ushort*)p;            p += hHalf * 2;
    float*  m    = (float*)p;             p += NPAD * 256 * 4;
    ushort* BgH  = (ushort*)p;            p += (size_t)1048576 * 2;
    ushort* BgL  = (ushort*)p;            p += (size_t)1048576 * 2;
    ushort* BwH  = (ushort*)p;            p += (size_t)L * 131072 * 2;
    ushort* BwL  = (ushort*)p;            p += (size_t)L * 131072 * 2;
    float*  bsum = (float*)p;             p += 512 * 4;
    float*  bni  = (float*)p;             p += 256 * 4;
    float*  bnh  = (float*)p;             p += 256 * 4;
    int*    ptr  = (int*)p;               p += (size_t)(N + 1) * 4;
    int*    cursor = (int*)p;             p += (size_t)N * 4;
    int*    bsumN  = (int*)p;             p += (size_t)NB * 4;
    int*    srcs   = (int*)p;             p += (size_t)E * 4;
    float*  wse    = (float*)p;           p += (size_t)E * 4;
    const size_t need_reduced = (size_t)(p - (char*)d_ws);
    ushort* HxL = (ushort*)p;             // optional hi/lo h planes
    ushort* HyL = (ushort*)(p + hHalf * 2);
    const size_t need_full = need_reduced + 2 * hHalf * 2;
    const int useHL = (ws_size >= need_full) ? 1 : 0;
    if (!useHL) { HxL = HxH; HyL = HyH; }  // never dereferenced when useHL=0

    detect_k<<<dim3(1), dim3(64), 0, stream>>>(d_in[0], d_in[1], flags);
    conv_h0_k<<<dim3((unsigned)NPAD), dim3(256), 0, stream>>>(
        d_in[0], HxH, HxL, flags, useHL, N, NPAD * 256);
    prep_k<<<dim3(4096), dim3(256), 0, stream>>>(
        d_in[3], d_in[4], d_in[5], d_in[6], d_in[7],
        BgH, BgL, BwH, BwL, bsum, bni, bnh, flags, L);

    zero_int_k<<<dim3(NB), dim3(256), 0, stream>>>(cursor, N);
    count_k<<<dim3((E + 255) / 256), dim3(256), 0, stream>>>(d_in[1], cursor, flags, E);
    scan1_k<<<dim3(NB), dim3(256), 0, stream>>>(cursor, ptr, bsumN, N);
    scan2_k<<<dim3(1), dim3(256), 0, stream>>>(bsumN, NB);
    scan3_k<<<dim3(NB), dim3(256), 0, stream>>>(ptr, cursor, bsumN, N, E);
    fill_k<<<dim3((E + 255) / 256), dim3(256), 0, stream>>>(
        d_in[1], d_in[2], cursor, srcs, wse, flags, E);

    const dim3 blk(256);
    const unsigned gGrid = 64u * (unsigned)((nRB + 7) / 8);
    ushort *HcH = HxH, *HcL = HxL, *HnH = HyH, *HnL = HyL;
    for (int l = 0; l < L; ++l) {
        m_gemm_k<<<dim3((unsigned)(2 * nRB)), blk, 0, stream>>>(
            HcH, HcL, BwH + (size_t)l * 131072, BwL + (size_t)l * 131072,
            m, flags, useHL, nRB);
        spmm_k<<<dim3((N + 3) / 4), blk, 0, stream>>>(m, ptr, srcs, wse, AGG, N);
        gates_k<<<dim3(gGrid), blk, 0, stream>>>(
            AGG, HcH, HcL, BgH, BgL, bsum, bni, bnh, HnH, HnL, flags, useHL, nRB);
        ushort* t;
        t = HcH; HcH = HnH; HnH = t;
        t = HcL; HcL = HnL; HnL = t;
    }
    final_k<<<dim3(N), blk, 0, stream>>>(
        HcH, HcL, d_in[8], d_in[9], d_out, flags, useHL, N);
}